// Round 12
// baseline (104.861 us; speedup 1.0000x reference)
//
#include <hip/hip_runtime.h>

#define BB 512
#define HH 1024
#define CC 256
#define WW 512

#define SMAX 8                 // samples staged per pass in pw path
#define WSPLIT 64
#define WCHUNK (WW / WSPLIT)   // 8 rows per pw block
#define ROWS_PER_WAVE (WCHUNK / 4)  // 2 contiguous rows per wave
#define PCS 4                  // samples per block in pc path
#define NPC (BB / PCS)         // 128 pc blocks
#define NPW (CC * WSPLIT)      // 16384 pw blocks
#define WTILE 4

typedef float f4 __attribute__((ext_vector_type(4)));

__device__ __forceinline__ f4 ntload(const f4* p) {
    return __builtin_nontemporal_load(p);
}

// Full-wave (64-lane) sum via DPP — pure VALU. Result valid in lane 63.
__device__ __forceinline__ float dpp_sum64(float v) {
    union { float f; int i; } u, t;
    u.f = v;
#define DPP_ADD(ctrl) \
    t.i = __builtin_amdgcn_update_dpp(0, u.i, (ctrl), 0xf, 0xf, true); u.f += t.f;
    DPP_ADD(0x111);  // row_shr:1
    DPP_ADD(0x112);  // row_shr:2
    DPP_ADD(0x114);  // row_shr:4
    DPP_ADD(0x118);  // row_shr:8
    DPP_ADD(0x142);  // row_bcast:15
    DPP_ADD(0x143);  // row_bcast:31
#undef DPP_ADD
    return u.f;
}

__device__ __forceinline__ float wave_reduce_sum(float v) {
    #pragma unroll
    for (int off = 32; off > 0; off >>= 1) v += __shfl_xor(v, off, 64);
    return v;
}
__device__ __forceinline__ float wave_reduce_max(float v) {
    #pragma unroll
    for (int off = 32; off > 0; off >>= 1) v = fmaxf(v, __shfl_xor(v, off, 64));
    return v;
}

__device__ __forceinline__ float dot4_acc(f4 a, f4 x, float acc) {
    acc = fmaf(a.x, x.x, acc);
    acc = fmaf(a.y, x.y, acc);
    acc = fmaf(a.z, x.z, acc);
    acc = fmaf(a.w, x.w, acc);
    return acc;
}

#define SMEM_FLOATS (SMAX * HH)

// blocks [0,NPC): p_c; blocks [NPC, NPC+NPW): pw logits
__global__ __launch_bounds__(256) void fused_kernel(const float* __restrict__ h_p,
                                                    const int* __restrict__ tcl,
                                                    const float* __restrict__ psi_w,
                                                    const float* __restrict__ phi_w,
                                                    const float* __restrict__ phi_b,
                                                    float* __restrict__ p_c,
                                                    float* __restrict__ logits_ws) {
    __shared__ __align__(16) float s_hp[SMEM_FLOATS];   // 32 KB
    __shared__ __align__(16) float s_aux[PCS * CC];     // 4 KB (pc logits)
    __shared__ int s_list[BB];
    __shared__ int s_wcnt[8];
    __shared__ float s_red[8];

    const int bid = blockIdx.x;
    const int tid = threadIdx.x;
    const int wave = tid >> 6;
    const int lane = tid & 63;

    if (bid < NPC) {
        // ================= p_c =================
        const int b0 = bid * PCS;
        for (int i = tid; i < PCS * (HH / 4); i += 256) {
            const int s = i >> 8;
            const int k = i & 255;
            ((f4*)(s_hp + s * HH))[k] = ((const f4*)(h_p + (size_t)(b0 + s) * HH))[k];
        }
        __syncthreads();

        for (int cg = 0; cg < 64 / WTILE; cg++) {
            const int c0 = wave * 64 + cg * WTILE;
            float acc[WTILE][PCS];
            #pragma unroll
            for (int a = 0; a < WTILE; a++)
                #pragma unroll
                for (int s = 0; s < PCS; s++) acc[a][s] = 0.f;

            #pragma unroll
            for (int i = 0; i < (HH / 4) / 64; i++) {
                const int k = lane + i * 64;
                f4 r0 = ((const f4*)(psi_w + (size_t)(c0 + 0) * HH))[k];
                f4 r1 = ((const f4*)(psi_w + (size_t)(c0 + 1) * HH))[k];
                f4 r2 = ((const f4*)(psi_w + (size_t)(c0 + 2) * HH))[k];
                f4 r3 = ((const f4*)(psi_w + (size_t)(c0 + 3) * HH))[k];
                #pragma unroll
                for (int s = 0; s < PCS; s++) {
                    f4 x = ((const f4*)(s_hp + s * HH))[k];
                    acc[0][s] = dot4_acc(r0, x, acc[0][s]);
                    acc[1][s] = dot4_acc(r1, x, acc[1][s]);
                    acc[2][s] = dot4_acc(r2, x, acc[2][s]);
                    acc[3][s] = dot4_acc(r3, x, acc[3][s]);
                }
            }
            #pragma unroll
            for (int a = 0; a < WTILE; a++)
                #pragma unroll
                for (int s = 0; s < PCS; s++) {
                    float v = dpp_sum64(acc[a][s]);
                    if (lane == 63) s_aux[s * CC + c0 + a] = v;
                }
        }
        __syncthreads();

        for (int s = 0; s < PCS; s++) {
            const float lv = s_aux[s * CC + tid];
            float m = wave_reduce_max(lv);
            if (lane == 0) s_red[wave] = m;
            __syncthreads();
            const float bm = fmaxf(fmaxf(s_red[0], s_red[1]), fmaxf(s_red[2], s_red[3]));
            const float e = expf(lv - bm);
            float sm = wave_reduce_sum(e);
            __syncthreads();
            if (lane == 0) s_red[wave] = sm;
            __syncthreads();
            const float bs = s_red[0] + s_red[1] + s_red[2] + s_red[3];
            p_c[(size_t)(b0 + s) * CC + tid] = e / bs;
            __syncthreads();
        }
        return;
    }

    // ================= pw logits =================
    const int id2 = bid - NPC;
    const int c = id2 >> 6;            // / WSPLIT
    const int split = id2 & (WSPLIT - 1);

    // ballot bucketing: deterministic ascending order, no atomics
    const int ca = tcl[tid];
    const int cb = tcl[tid + 256];
    const unsigned long long m0 = __ballot(ca == c);
    const unsigned long long m1 = __ballot(cb == c);
    if (lane == 0) { s_wcnt[wave] = __popcll(m0); s_wcnt[4 + wave] = __popcll(m1); }
    __syncthreads();
    int tot = 0, base0 = 0, base1 = 0;
    #pragma unroll
    for (int i = 0; i < 8; i++) {
        const int v = s_wcnt[i];
        if (i < wave) base0 += v;
        if (i < 4 + wave) base1 += v;
        tot += v;
    }
    const unsigned long long below = (1ull << lane) - 1ull;
    if (ca == c) s_list[base0 + __popcll(m0 & below)] = tid;
    if (cb == c) s_list[base1 + __popcll(m1 & below)] = tid + 256;
    __syncthreads();
    const int n = tot;
    if (n == 0) return;

    const float* __restrict__ base = phi_w + (size_t)c * WW * HH;
    const int wbase = split * WCHUNK + wave * ROWS_PER_WAVE;  // 2 contiguous rows

    for (int s0 = 0; s0 < n; s0 += SMAX) {
        const int ns = min(SMAX, n - s0);

        // ---- prime rows 0 (A) and 1 (B) + biases BEFORE staging: their HBM
        // latency hides under the h_p stage + syncs.
        const f4* pA = (const f4*)(base + (size_t)wbase * HH);        // even row
        const f4* pB = (const f4*)(base + (size_t)(wbase + 1) * HH);  // odd row
        const float* bp = phi_b + (size_t)c * WW + wbase;
        f4 A0 = ntload(pA + lane);
        f4 A1 = ntload(pA + lane + 64);
        f4 A2 = ntload(pA + lane + 128);
        f4 A3 = ntload(pA + lane + 192);
        f4 B0 = ntload(pB + lane);
        f4 B1 = ntload(pB + lane + 64);
        f4 B2 = ntload(pB + lane + 128);
        f4 B3 = ntload(pB + lane + 192);
        float biasA = bp[0];
        float biasB = bp[1];

        __syncthreads();   // previous pass done with s_hp
        for (int i = tid; i < ns * (HH / 4); i += 256) {
            const int s = i >> 8;
            const int k = i & 255;
            ((f4*)(s_hp + s * HH))[k] = ((const f4*)(h_p + (size_t)s_list[s0 + s] * HH))[k];
        }
        __syncthreads();

        // ---- 2 rows, both primed: vmcnt never drains mid-stream.
        for (int r = 0; r < ROWS_PER_WAVE; r += 2) {
            const int wA = wbase + r;
            for (int s = 0; s < ns; s++) {
                const f4* __restrict__ xs = (const f4*)(s_hp + s * HH);
                float acc = 0.f;
                acc = dot4_acc(A0, xs[lane], acc);
                acc = dot4_acc(A1, xs[lane + 64], acc);
                acc = dot4_acc(A2, xs[lane + 128], acc);
                acc = dot4_acc(A3, xs[lane + 192], acc);
                const float v = dpp_sum64(acc);
                if (lane == 63) logits_ws[(size_t)s_list[s0 + s] * WW + wA] = v + biasA;
            }
            const int wB = wA + 1;
            for (int s = 0; s < ns; s++) {
                const f4* __restrict__ xs = (const f4*)(s_hp + s * HH);
                float acc = 0.f;
                acc = dot4_acc(B0, xs[lane], acc);
                acc = dot4_acc(B1, xs[lane + 64], acc);
                acc = dot4_acc(B2, xs[lane + 128], acc);
                acc = dot4_acc(B3, xs[lane + 192], acc);
                const float v = dpp_sum64(acc);
                if (lane == 63) logits_ws[(size_t)s_list[s0 + s] * WW + wB] = v + biasB;
            }
        }
    }
}

// ---------- p_w: mask + softmax over W ----------
__global__ __launch_bounds__(512) void pw_softmax_kernel(const int* __restrict__ tcl,
                                                         const int* __restrict__ csz,
                                                         const float* __restrict__ logits_ws,
                                                         float* __restrict__ p_w) {
    __shared__ float red[8];
    const int b = blockIdx.x;
    const int tid = threadIdx.x;
    const int wave = tid >> 6;
    const int lane = tid & 63;

    const int c = tcl[b];
    const int size = csz[c];

    const float lv = logits_ws[(size_t)b * WW + tid];
    const bool valid = tid < size;
    const float mask_pos = valid ? 1.f : -1.f;
    const float mask_neg = valid ? 1.f : -1e5f;
    const float filt = (lv > 0.f ? lv : lv * mask_pos) * mask_neg;

    float m = wave_reduce_max(filt);
    if (lane == 0) red[wave] = m;
    __syncthreads();
    float bm = red[0];
    #pragma unroll
    for (int i = 1; i < 8; i++) bm = fmaxf(bm, red[i]);
    const float e = expf(filt - bm);
    float s = wave_reduce_sum(e);
    __syncthreads();
    if (lane == 0) red[wave] = s;
    __syncthreads();
    float bs = 0.f;
    #pragma unroll
    for (int i = 0; i < 8; i++) bs += red[i];
    p_w[(size_t)b * WW + tid] = e / bs;
}

extern "C" void kernel_launch(void* const* d_in, const int* in_sizes, int n_in,
                              void* d_out, int out_size, void* d_ws, size_t ws_size,
                              hipStream_t stream) {
    const float* h_p   = (const float*)d_in[0];
    const int*   tcl   = (const int*)d_in[1];
    const int*   csz   = (const int*)d_in[2];
    const float* psi_w = (const float*)d_in[3];
    const float* phi_w = (const float*)d_in[4];
    const float* phi_b = (const float*)d_in[5];

    float* p_c = (float*)d_out;                    // [B, C]
    float* p_w = (float*)d_out + (size_t)BB * CC;  // [B, W]

    float* logits_ws = (float*)d_ws;               // BB*WW floats (1 MB)

    fused_kernel<<<NPC + NPW, 256, 0, stream>>>(h_p, tcl, psi_w, phi_w, phi_b, p_c, logits_ws);
    pw_softmax_kernel<<<BB, 512, 0, stream>>>(tcl, csz, logits_ws, p_w);
}

// Round 13
// 90.344 us; speedup vs baseline: 1.1607x; 1.1607x over previous
//
#include <hip/hip_runtime.h>

#define BB 512
#define HH 1024
#define CC 256
#define WW 512

#define SMAX 8                 // samples staged per pass in pw path
#define WSPLIT 32
#define WCHUNK (WW / WSPLIT)   // 16 rows per pw block
#define ROWS_PER_WAVE (WCHUNK / 4)  // 4 contiguous rows per wave
#define PCS 4                  // samples per block in pc path
#define NPC (BB / PCS)         // 128 pc blocks
#define NPW (CC * WSPLIT)      // 8192 pw blocks
#define WTILE 4

typedef float f4 __attribute__((ext_vector_type(4)));

__device__ __forceinline__ f4 ntload(const f4* p) {
    return __builtin_nontemporal_load(p);
}

// Full-wave (64-lane) sum via DPP — pure VALU. Result valid in lane 63.
__device__ __forceinline__ float dpp_sum64(float v) {
    union { float f; int i; } u, t;
    u.f = v;
#define DPP_ADD(ctrl) \
    t.i = __builtin_amdgcn_update_dpp(0, u.i, (ctrl), 0xf, 0xf, true); u.f += t.f;
    DPP_ADD(0x111);  // row_shr:1
    DPP_ADD(0x112);  // row_shr:2
    DPP_ADD(0x114);  // row_shr:4
    DPP_ADD(0x118);  // row_shr:8
    DPP_ADD(0x142);  // row_bcast:15
    DPP_ADD(0x143);  // row_bcast:31
#undef DPP_ADD
    return u.f;
}

__device__ __forceinline__ float wave_reduce_sum(float v) {
    #pragma unroll
    for (int off = 32; off > 0; off >>= 1) v += __shfl_xor(v, off, 64);
    return v;
}
__device__ __forceinline__ float wave_reduce_max(float v) {
    #pragma unroll
    for (int off = 32; off > 0; off >>= 1) v = fmaxf(v, __shfl_xor(v, off, 64));
    return v;
}

__device__ __forceinline__ float dot4_acc(f4 a, f4 x, float acc) {
    acc = fmaf(a.x, x.x, acc);
    acc = fmaf(a.y, x.y, acc);
    acc = fmaf(a.z, x.z, acc);
    acc = fmaf(a.w, x.w, acc);
    return acc;
}

#define SMEM_FLOATS (SMAX * HH)

// blocks [0,NPC): p_c; blocks [NPC, NPC+NPW): pw logits
__global__ __launch_bounds__(256) void fused_kernel(const float* __restrict__ h_p,
                                                    const int* __restrict__ tcl,
                                                    const float* __restrict__ psi_w,
                                                    const float* __restrict__ phi_w,
                                                    const float* __restrict__ phi_b,
                                                    float* __restrict__ p_c,
                                                    float* __restrict__ logits_ws) {
    __shared__ __align__(16) float s_hp[SMEM_FLOATS];   // 32 KB
    __shared__ __align__(16) float s_aux[PCS * CC];     // 4 KB (pc logits)
    __shared__ int s_list[BB];
    __shared__ int s_wcnt[8];
    __shared__ float s_red[8];

    const int bid = blockIdx.x;
    const int tid = threadIdx.x;
    const int wave = tid >> 6;
    const int lane = tid & 63;

    if (bid < NPC) {
        // ================= p_c =================
        const int b0 = bid * PCS;
        for (int i = tid; i < PCS * (HH / 4); i += 256) {
            const int s = i >> 8;
            const int k = i & 255;
            ((f4*)(s_hp + s * HH))[k] = ((const f4*)(h_p + (size_t)(b0 + s) * HH))[k];
        }
        __syncthreads();

        for (int cg = 0; cg < 64 / WTILE; cg++) {
            const int c0 = wave * 64 + cg * WTILE;
            float acc[WTILE][PCS];
            #pragma unroll
            for (int a = 0; a < WTILE; a++)
                #pragma unroll
                for (int s = 0; s < PCS; s++) acc[a][s] = 0.f;

            #pragma unroll
            for (int i = 0; i < (HH / 4) / 64; i++) {
                const int k = lane + i * 64;
                f4 r0 = ((const f4*)(psi_w + (size_t)(c0 + 0) * HH))[k];
                f4 r1 = ((const f4*)(psi_w + (size_t)(c0 + 1) * HH))[k];
                f4 r2 = ((const f4*)(psi_w + (size_t)(c0 + 2) * HH))[k];
                f4 r3 = ((const f4*)(psi_w + (size_t)(c0 + 3) * HH))[k];
                #pragma unroll
                for (int s = 0; s < PCS; s++) {
                    f4 x = ((const f4*)(s_hp + s * HH))[k];
                    acc[0][s] = dot4_acc(r0, x, acc[0][s]);
                    acc[1][s] = dot4_acc(r1, x, acc[1][s]);
                    acc[2][s] = dot4_acc(r2, x, acc[2][s]);
                    acc[3][s] = dot4_acc(r3, x, acc[3][s]);
                }
            }
            #pragma unroll
            for (int a = 0; a < WTILE; a++)
                #pragma unroll
                for (int s = 0; s < PCS; s++) {
                    float v = dpp_sum64(acc[a][s]);
                    if (lane == 63) s_aux[s * CC + c0 + a] = v;
                }
        }
        __syncthreads();

        for (int s = 0; s < PCS; s++) {
            const float lv = s_aux[s * CC + tid];
            float m = wave_reduce_max(lv);
            if (lane == 0) s_red[wave] = m;
            __syncthreads();
            const float bm = fmaxf(fmaxf(s_red[0], s_red[1]), fmaxf(s_red[2], s_red[3]));
            const float e = expf(lv - bm);
            float sm = wave_reduce_sum(e);
            __syncthreads();
            if (lane == 0) s_red[wave] = sm;
            __syncthreads();
            const float bs = s_red[0] + s_red[1] + s_red[2] + s_red[3];
            p_c[(size_t)(b0 + s) * CC + tid] = e / bs;
            __syncthreads();
        }
        return;
    }

    // ================= pw logits =================
    const int id2 = bid - NPC;
    const int c = id2 >> 5;            // / WSPLIT
    const int split = id2 & (WSPLIT - 1);

    // ballot bucketing: deterministic ascending order, no atomics
    const int ca = tcl[tid];
    const int cb = tcl[tid + 256];
    const unsigned long long m0 = __ballot(ca == c);
    const unsigned long long m1 = __ballot(cb == c);
    if (lane == 0) { s_wcnt[wave] = __popcll(m0); s_wcnt[4 + wave] = __popcll(m1); }
    __syncthreads();
    int tot = 0, base0 = 0, base1 = 0;
    #pragma unroll
    for (int i = 0; i < 8; i++) {
        const int v = s_wcnt[i];
        if (i < wave) base0 += v;
        if (i < 4 + wave) base1 += v;
        tot += v;
    }
    const unsigned long long below = (1ull << lane) - 1ull;
    if (ca == c) s_list[base0 + __popcll(m0 & below)] = tid;
    if (cb == c) s_list[base1 + __popcll(m1 & below)] = tid + 256;
    __syncthreads();
    const int n = tot;
    if (n == 0) return;

    const float* __restrict__ base = phi_w + (size_t)c * WW * HH;
    const int wbase = split * WCHUNK + wave * ROWS_PER_WAVE;  // 4 contiguous rows

    for (int s0 = 0; s0 < n; s0 += SMAX) {
        const int ns = min(SMAX, n - s0);

        // ---- prime rows 0 (A) and 1 (B) + biases BEFORE staging: their HBM
        // latency hides under the h_p stage + syncs.
        const f4* pA = (const f4*)(base + (size_t)wbase * HH);        // even rows
        const f4* pB = (const f4*)(base + (size_t)(wbase + 1) * HH);  // odd rows
        const float* bp = phi_b + (size_t)c * WW + wbase;
        f4 A0 = ntload(pA + lane);
        f4 A1 = ntload(pA + lane + 64);
        f4 A2 = ntload(pA + lane + 128);
        f4 A3 = ntload(pA + lane + 192);
        f4 B0 = ntload(pB + lane);
        f4 B1 = ntload(pB + lane + 64);
        f4 B2 = ntload(pB + lane + 128);
        f4 B3 = ntload(pB + lane + 192);
        float biasA = bp[0];
        float biasB = bp[1];
        pA += 2 * (HH / 4);   // advance 2 rows
        pB += 2 * (HH / 4);

        __syncthreads();   // previous pass done with s_hp
        for (int i = tid; i < ns * (HH / 4); i += 256) {
            const int s = i >> 8;
            const int k = i & 255;
            ((f4*)(s_hp + s * HH))[k] = ((const f4*)(h_p + (size_t)s_list[s0 + s] * HH))[k];
        }
        __syncthreads();

        // ---- 2-deep parity pipeline: never drains vmcnt to 0.
        for (int r = 0; r < ROWS_PER_WAVE; r += 2) {
            const int wA = wbase + r;
            for (int s = 0; s < ns; s++) {
                const f4* __restrict__ xs = (const f4*)(s_hp + s * HH);
                float acc = 0.f;
                acc = dot4_acc(A0, xs[lane], acc);
                acc = dot4_acc(A1, xs[lane + 64], acc);
                acc = dot4_acc(A2, xs[lane + 128], acc);
                acc = dot4_acc(A3, xs[lane + 192], acc);
                const float v = dpp_sum64(acc);
                if (lane == 63) logits_ws[(size_t)s_list[s0 + s] * WW + wA] = v + biasA;
            }
            if (r + 2 < ROWS_PER_WAVE) {
                A0 = ntload(pA + lane);
                A1 = ntload(pA + lane + 64);
                A2 = ntload(pA + lane + 128);
                A3 = ntload(pA + lane + 192);
                biasA = bp[r + 2];
                pA += 2 * (HH / 4);
            }
            const int wB = wA + 1;
            for (int s = 0; s < ns; s++) {
                const f4* __restrict__ xs = (const f4*)(s_hp + s * HH);
                float acc = 0.f;
                acc = dot4_acc(B0, xs[lane], acc);
                acc = dot4_acc(B1, xs[lane + 64], acc);
                acc = dot4_acc(B2, xs[lane + 128], acc);
                acc = dot4_acc(B3, xs[lane + 192], acc);
                const float v = dpp_sum64(acc);
                if (lane == 63) logits_ws[(size_t)s_list[s0 + s] * WW + wB] = v + biasB;
            }
            if (r + 2 < ROWS_PER_WAVE) {
                B0 = ntload(pB + lane);
                B1 = ntload(pB + lane + 64);
                B2 = ntload(pB + lane + 128);
                B3 = ntload(pB + lane + 192);
                biasB = bp[r + 3];
                pB += 2 * (HH / 4);
            }
        }
    }
}

// ---------- p_w: mask + softmax over W ----------
__global__ __launch_bounds__(512) void pw_softmax_kernel(const int* __restrict__ tcl,
                                                         const int* __restrict__ csz,
                                                         const float* __restrict__ logits_ws,
                                                         float* __restrict__ p_w) {
    __shared__ float red[8];
    const int b = blockIdx.x;
    const int tid = threadIdx.x;
    const int wave = tid >> 6;
    const int lane = tid & 63;

    const int c = tcl[b];
    const int size = csz[c];

    const float lv = logits_ws[(size_t)b * WW + tid];
    const bool valid = tid < size;
    const float mask_pos = valid ? 1.f : -1.f;
    const float mask_neg = valid ? 1.f : -1e5f;
    const float filt = (lv > 0.f ? lv : lv * mask_pos) * mask_neg;

    float m = wave_reduce_max(filt);
    if (lane == 0) red[wave] = m;
    __syncthreads();
    float bm = red[0];
    #pragma unroll
    for (int i = 1; i < 8; i++) bm = fmaxf(bm, red[i]);
    const float e = expf(filt - bm);
    float s = wave_reduce_sum(e);
    __syncthreads();
    if (lane == 0) red[wave] = s;
    __syncthreads();
    float bs = 0.f;
    #pragma unroll
    for (int i = 0; i < 8; i++) bs += red[i];
    p_w[(size_t)b * WW + tid] = e / bs;
}

extern "C" void kernel_launch(void* const* d_in, const int* in_sizes, int n_in,
                              void* d_out, int out_size, void* d_ws, size_t ws_size,
                              hipStream_t stream) {
    const float* h_p   = (const float*)d_in[0];
    const int*   tcl   = (const int*)d_in[1];
    const int*   csz   = (const int*)d_in[2];
    const float* psi_w = (const float*)d_in[3];
    const float* phi_w = (const float*)d_in[4];
    const float* phi_b = (const float*)d_in[5];

    float* p_c = (float*)d_out;                    // [B, C]
    float* p_w = (float*)d_out + (size_t)BB * CC;  // [B, W]

    float* logits_ws = (float*)d_ws;               // BB*WW floats (1 MB)

    fused_kernel<<<NPC + NPW, 256, 0, stream>>>(h_p, tcl, psi_w, phi_w, phi_b, p_c, logits_ws);
    pw_softmax_kernel<<<BB, 512, 0, stream>>>(tcl, csz, logits_ws, p_w);
}